// Round 8
// baseline (171.017 us; speedup 1.0000x reference)
//
#include <hip/hip_runtime.h>

#define BATCH 32
#define SEQL 4096
#define NCH 128
#define CHUNK 32
#define NCHUNK (SEQL / CHUNK)    // 128 chunks per batch row
#define GSTEP 8                  // output steps per LDS flush group
#define NG (CHUNK / GSTEP)       // 4 groups
#define ROWF 257                 // floats per output step
#define EM 0.9f
#define EM4 0.6561f              // 0.9^4
#define EMC 0.034336838202925f   // 0.9^32 (chunk decay)
// one-hot (p) side-term constants:
#define C0 0.0729f
#define C1 0.081f
#define C2 0.09f
#define C3 0.1f
// coefficients for pre-scaled (0.1*x) inputs:
#define D0 0.729f
#define D1 0.81f
#define D2 0.9f

// Exact chunk-scan decomposition (EMA is linear):
//   L_k   = sum_{t in chunk k} 0.9^{end_k - t} * 0.1 * x[t]   (phase 1)
//   carry_k = 0.9^32 * carry_{k-1} + L_k                      (phase 2 scan)
//   outputs of chunk k evolve from exact carry_{k-1}          (phase 3)
// No warmup anywhere: 262K total evolve steps vs 524K in the warmup scheme,
// and results are exact up to f32 rounding. probs normalizer == 1 (EMA
// preserves one-hot row sums) => skip it. Output stores go through an LDS
// bounce (row stride 1028 B is not sector-aligned; dense dwordx4 flush).

// ---- phase 1: per-chunk local EMA sums -> Lws[b][k][257] ----
__global__ __launch_bounds__(128) void mpe_phase1(
    const float* __restrict__ ts,
    const int* __restrict__ labels,
    const float* __restrict__ amounts,
    float* __restrict__ Lws)
{
    const int c = threadIdx.x;
    const int k = blockIdx.x;
    const int b = blockIdx.y;
    const int s = k * CHUNK;

    __shared__ float2 s_ad[CHUNK];   // {0.1*amt, 0.1*clipped dt}
    __shared__ int    s_lab[CHUNK];

    const size_t rowbase = (size_t)b * SEQL;
    const float* tsr = ts + rowbase;

    if (c < CHUNK) {
        int gl = s + c;
        float d = (gl > 0) ? fminf(tsr[gl] - tsr[gl - 1], 100.f) : 0.f;
        s_ad[c] = make_float2(0.1f * amounts[rowbase + gl], 0.1f * d);
        s_lab[c] = labels[rowbase + gl];
    }
    __syncthreads();

    float p = 0.f, a = 0.f, dm = 0.f;
    int i = 0;
    if (k == 0) {
        // exact init at global position 0: carry = x[0]
        bool mine = (c == s_lab[0]);
        p = mine ? 1.f : 0.f;
        a = mine ? 10.f * s_ad[0].x : 0.f;   // undo the 0.1 pre-scale (~1ulp)
        dm = 0.f;                            // first delta is 0
        i = 1;
    }

    // peel to 4-step alignment, then grouped 4-step evolve (chain cut 4x)
    int rem = (CHUNK - i) & 3;
    for (int t = 0; t < rem; ++t, ++i) {
        bool mine = (c == s_lab[i]);
        float2 ad = s_ad[i];
        p = fmaf(p, EM, mine ? 0.1f : 0.f);
        a = fmaf(a, EM, mine ? ad.x : 0.f);
        dm = fmaf(dm, EM, ad.y);
    }
    for (; i < CHUNK; i += 4) {
        int l0 = s_lab[i], l1 = s_lab[i+1], l2 = s_lab[i+2], l3 = s_lab[i+3];
        float2 a0 = s_ad[i], a1 = s_ad[i+1], a2 = s_ad[i+2], a3 = s_ad[i+3];
        bool m0 = (c == l0), m1 = (c == l1), m2 = (c == l2), m3 = (c == l3);
        float tp = (m0 ? C0 : 0.f) + (m1 ? C1 : 0.f)
                 + (m2 ? C2 : 0.f) + (m3 ? C3 : 0.f);
        float ta = (m0 ? D0 * a0.x : 0.f) + (m1 ? D1 * a1.x : 0.f)
                 + (m2 ? D2 * a2.x : 0.f) + (m3 ? a3.x : 0.f);
        float td = fmaf(D0, a0.y, fmaf(D1, a1.y, fmaf(D2, a2.y, a3.y)));
        p = fmaf(p, EM4, tp);
        a = fmaf(a, EM4, ta);
        dm = fmaf(dm, EM4, td);
    }

    float* Lrow = Lws + ((size_t)b * NCHUNK + k) * ROWF;
    Lrow[1 + c] = p;
    Lrow[1 + NCH + c] = a;
    if (c == 0) Lrow[0] = dm;
}

// ---- phase 2: serial scan over chunks (tiny) -> Cws[b][k][257] ----
__global__ __launch_bounds__(320) void mpe_phase2(
    const float* __restrict__ Lws, float* __restrict__ Cws)
{
    const int d = threadIdx.x;
    const int b = blockIdx.x;
    if (d >= ROWF) return;
    const float* Lb = Lws + (size_t)b * NCHUNK * ROWF + d;
    float*       Cb = Cws + (size_t)b * NCHUNK * ROWF + d;
    float v = Lb[0];
    Cb[0] = v;
    #pragma unroll 4
    for (int k = 1; k < NCHUNK; ++k) {
        v = fmaf(v, EMC, Lb[(size_t)k * ROWF]);
        Cb[(size_t)k * ROWF] = v;
    }
}

// ---- phase 3: outputs from exact carries; zero warmup ----
__global__ __launch_bounds__(128) void mpe_phase3(
    const float* __restrict__ ts,
    const int* __restrict__ labels,
    const float* __restrict__ amounts,
    const float* __restrict__ Cws,
    float* __restrict__ out)
{
    const int c = threadIdx.x;
    const int k = blockIdx.x;
    const int b = blockIdx.y;
    const int s = k * CHUNK;

    __shared__ float2 s_ad[CHUNK];
    __shared__ int    s_lab[CHUNK];
    __shared__ __align__(16) float obuf[GSTEP * ROWF];   // 8224 B

    const size_t rowbase = (size_t)b * SEQL;
    const float* tsr = ts + rowbase;

    if (c < CHUNK) {
        int gl = s + c;
        float d = (gl > 0) ? fminf(tsr[gl] - tsr[gl - 1], 100.f) : 0.f;
        s_ad[c] = make_float2(0.1f * amounts[rowbase + gl], 0.1f * d);
        s_lab[c] = labels[rowbase + gl];
    }

    float p = 0.f, a = 0.f, dm = 0.f;
    if (k > 0) {
        const float* Crow = Cws + ((size_t)b * NCHUNK + (k - 1)) * ROWF;
        p = Crow[1 + c];
        a = Crow[1 + NCH + c];
        dm = Crow[0];            // uniform broadcast load
    }
    __syncthreads();

    for (int g = 0; g < NG; ++g) {
        const int base = g * GSTEP;
        #pragma unroll
        for (int t = 0; t < GSTEP; ++t) {
            const int idx = base + t;
            if (k == 0 && g == 0 && t == 0) {
                // row 0 is the exact-init state e[0] = x[0]
                bool mine = (c == s_lab[0]);
                p = mine ? 1.f : 0.f;
                a = mine ? 10.f * s_ad[0].x : 0.f;
                dm = 0.f;
            } else {
                bool mine = (c == s_lab[idx]);
                float2 ad = s_ad[idx];
                p = fmaf(p, EM, mine ? 0.1f : 0.f);
                a = fmaf(a, EM, mine ? ad.x : 0.f);
                dm = fmaf(dm, EM, ad.y);
            }
            obuf[t * ROWF + 1 + c] = p;
            obuf[t * ROWF + 1 + NCH + c] = __fdividef(a, fmaxf(p, 1e-6f));
            if (c == 0) obuf[t * ROWF] = dm;
        }
        __syncthreads();

        float4* gout = (float4*)(out + (rowbase + s + base) * (size_t)ROWF);
        const float4* ob4 = (const float4*)obuf;
        for (int q = c; q < GSTEP * ROWF / 4; q += 128)
            gout[q] = ob4[q];
        __syncthreads();
    }
}

extern "C" void kernel_launch(void* const* d_in, const int* in_sizes, int n_in,
                              void* d_out, int out_size, void* d_ws, size_t ws_size,
                              hipStream_t stream) {
    const float* ts      = (const float*)d_in[0];
    const int*   labels  = (const int*)d_in[1];
    const float* amounts = (const float*)d_in[2];
    float* out = (float*)d_out;

    float* Lws = (float*)d_ws;                                   // [32][128][257]
    float* Cws = Lws + (size_t)BATCH * NCHUNK * ROWF;            // [32][128][257]

    dim3 grid(NCHUNK, BATCH);                                    // 128 x 32
    mpe_phase1<<<grid, 128, 0, stream>>>(ts, labels, amounts, Lws);
    mpe_phase2<<<dim3(BATCH), 320, 0, stream>>>(Lws, Cws);
    mpe_phase3<<<grid, 128, 0, stream>>>(ts, labels, amounts, Cws, out);
}

// Round 9
// 159.157 us; speedup vs baseline: 1.0745x; 1.0745x over previous
//
#include <hip/hip_runtime.h>

#define BATCH 32
#define SEQL 4096
#define NCH 128
#define CHUNK 64
#define NCHUNK (SEQL / CHUNK)    // 64 chunks per batch row
#define GSTEP 8                  // output steps per LDS flush group
#define NG (CHUNK / GSTEP)       // 8 groups
#define ROWF 257                 // floats per output row
#define EM 0.9f
#define EM4 0.6561f              // 0.9^4
// chunk decay D = 0.9^64 and its Kogge-Stone powers:
#define DP1 1.17901846e-3f       // 0.9^64
#define DP2 1.39008452e-6f       // 0.9^128
#define DP4 1.93233499e-12f      // 0.9^256
#define DP8 3.73391806e-24f      // 0.9^512  (0.9^1024 underflows f32 -> skip o>=16)
// one-hot (p) side-term constants:
#define C0 0.0729f
#define C1 0.081f
#define C2 0.09f
#define C3 0.1f
// coefficients for pre-scaled (0.1*x) inputs:
#define D0 0.729f
#define D1 0.81f
#define D2 0.9f

// Exact chunk-scan decomposition (EMA is linear):
//   P1: L_k = 64-step local weighted sum per (b,chunk)      [2048 blocks]
//   P2: S_k = D*S_{k-1} + L_k  -- Kogge-Stone, 1 chunk/lane [8224 wave-scans]
//   P3: outputs of chunk k evolve from exact carry S_{k-1}  [2048 blocks]
// Zero warmup, exact to f32 rounding. probs normalizer == 1 (EMA preserves
// one-hot row sums) => skip it. Stores go through an LDS bounce (row stride
// 1028 B is ≡4 mod 64 -> direct stores would partial-sector RMW).

// ---- phase 1: per-chunk local EMA sums -> Lws[b][k][257] ----
__global__ __launch_bounds__(128) void mpe_phase1(
    const float* __restrict__ ts,
    const int* __restrict__ labels,
    const float* __restrict__ amounts,
    float* __restrict__ Lws)
{
    const int c = threadIdx.x;
    const int k = blockIdx.x;
    const int b = blockIdx.y;
    const int s = k * CHUNK;

    __shared__ float2 s_ad[CHUNK];   // {0.1*amt, 0.1*clipped dt}
    __shared__ int    s_lab[CHUNK];

    const size_t rowbase = (size_t)b * SEQL;
    const float* tsr = ts + rowbase;

    if (c < CHUNK) {
        int gl = s + c;
        float d = (gl > 0) ? fminf(tsr[gl] - tsr[gl - 1], 100.f) : 0.f;
        s_ad[c] = make_float2(0.1f * amounts[rowbase + gl], 0.1f * d);
        s_lab[c] = labels[rowbase + gl];
    }
    __syncthreads();

    float p = 0.f, a = 0.f, dm = 0.f;
    int i = 0;
    if (k == 0) {
        // exact init at global position 0: carry = x[0]
        bool mine = (c == s_lab[0]);
        p = mine ? 1.f : 0.f;
        a = mine ? 10.f * s_ad[0].x : 0.f;   // undo 0.1 pre-scale (~1ulp)
        dm = 0.f;
        i = 1;
    }

    int rem = (CHUNK - i) & 3;               // peel to 4-step alignment
    for (int t = 0; t < rem; ++t, ++i) {
        bool mine = (c == s_lab[i]);
        float2 ad = s_ad[i];
        p = fmaf(p, EM, mine ? 0.1f : 0.f);
        a = fmaf(a, EM, mine ? ad.x : 0.f);
        dm = fmaf(dm, EM, ad.y);
    }
    for (; i < CHUNK; i += 4) {              // grouped: chain cut 4x
        int l0 = s_lab[i], l1 = s_lab[i+1], l2 = s_lab[i+2], l3 = s_lab[i+3];
        float2 a0 = s_ad[i], a1 = s_ad[i+1], a2 = s_ad[i+2], a3 = s_ad[i+3];
        bool m0 = (c == l0), m1 = (c == l1), m2 = (c == l2), m3 = (c == l3);
        float tp = (m0 ? C0 : 0.f) + (m1 ? C1 : 0.f)
                 + (m2 ? C2 : 0.f) + (m3 ? C3 : 0.f);
        float ta = (m0 ? D0 * a0.x : 0.f) + (m1 ? D1 * a1.x : 0.f)
                 + (m2 ? D2 * a2.x : 0.f) + (m3 ? a3.x : 0.f);
        float td = fmaf(D0, a0.y, fmaf(D1, a1.y, fmaf(D2, a2.y, a3.y)));
        p = fmaf(p, EM4, tp);
        a = fmaf(a, EM4, ta);
        dm = fmaf(dm, EM4, td);
    }

    float* Lrow = Lws + ((size_t)b * NCHUNK + k) * ROWF;
    Lrow[1 + c] = p;
    Lrow[1 + NCH + c] = a;
    if (c == 0) Lrow[0] = dm;
}

// ---- phase 2: Kogge-Stone weighted scan; writes EXCLUSIVE carry ----
// One 64-lane wave per (b,d) row; lane k holds chunk k. 8224 rows total.
__global__ __launch_bounds__(256) void mpe_phase2(
    const float* __restrict__ Lws, float* __restrict__ Cws)
{
    const int lane = threadIdx.x & 63;
    const int wid = threadIdx.x >> 6;                 // 0..3
    const int row = blockIdx.x * 4 + wid;             // (b,d) flat
    if (row >= BATCH * ROWF) return;
    const int b = row / ROWF;
    const int d = row - b * ROWF;
    const size_t base = ((size_t)b * NCHUNK) * ROWF + d;

    float v = Lws[base + (size_t)lane * ROWF];
    float t;
    t = __shfl_up(v, 1);  if (lane >= 1) v = fmaf(t, DP1, v);
    t = __shfl_up(v, 2);  if (lane >= 2) v = fmaf(t, DP2, v);
    t = __shfl_up(v, 4);  if (lane >= 4) v = fmaf(t, DP4, v);
    t = __shfl_up(v, 8);  if (lane >= 8) v = fmaf(t, DP8, v);
    // offsets 16/32 carry weight 0.9^1024 / 0.9^2048 == 0 in f32: skip.
    t = __shfl_up(v, 1);                              // exclusive shift
    Cws[base + (size_t)lane * ROWF] = (lane == 0) ? 0.f : t;
}

// ---- phase 3: outputs from exact carries; zero warmup ----
__global__ __launch_bounds__(128) void mpe_phase3(
    const float* __restrict__ ts,
    const int* __restrict__ labels,
    const float* __restrict__ amounts,
    const float* __restrict__ Cws,
    float* __restrict__ out)
{
    const int c = threadIdx.x;
    const int k = blockIdx.x;
    const int b = blockIdx.y;
    const int s = k * CHUNK;

    __shared__ float2 s_ad[CHUNK];
    __shared__ int    s_lab[CHUNK];
    __shared__ __align__(16) float obuf[GSTEP * ROWF];   // 8224 B

    const size_t rowbase = (size_t)b * SEQL;
    const float* tsr = ts + rowbase;

    // exact carry into this chunk (exclusive scan result)
    const float* Crow = Cws + ((size_t)b * NCHUNK + k) * ROWF;
    float p = Crow[1 + c];
    float a = Crow[1 + NCH + c];
    float dm = Crow[0];

    if (c < CHUNK) {
        int gl = s + c;
        float d = (gl > 0) ? fminf(tsr[gl] - tsr[gl - 1], 100.f) : 0.f;
        s_ad[c] = make_float2(0.1f * amounts[rowbase + gl], 0.1f * d);
        s_lab[c] = labels[rowbase + gl];
    }
    __syncthreads();

    for (int g = 0; g < NG; ++g) {
        const int base = g * GSTEP;
        #pragma unroll
        for (int t = 0; t < GSTEP; ++t) {
            const int idx = base + t;
            if (k == 0 && g == 0 && t == 0) {
                // row 0 is the exact-init state e[0] = x[0]
                bool mine = (c == s_lab[0]);
                p = mine ? 1.f : 0.f;
                a = mine ? 10.f * s_ad[0].x : 0.f;
                dm = 0.f;
            } else {
                bool mine = (c == s_lab[idx]);
                float2 ad = s_ad[idx];
                p = fmaf(p, EM, mine ? 0.1f : 0.f);
                a = fmaf(a, EM, mine ? ad.x : 0.f);
                dm = fmaf(dm, EM, ad.y);
            }
            obuf[t * ROWF + 1 + c] = p;
            obuf[t * ROWF + 1 + NCH + c] = __fdividef(a, fmaxf(p, 1e-6f));
            if (c == 0) obuf[t * ROWF] = dm;
        }
        __syncthreads();

        float4* gout = (float4*)(out + (rowbase + s + base) * (size_t)ROWF);
        const float4* ob4 = (const float4*)obuf;
        for (int q = c; q < GSTEP * ROWF / 4; q += 128)
            gout[q] = ob4[q];
        __syncthreads();
    }
}

extern "C" void kernel_launch(void* const* d_in, const int* in_sizes, int n_in,
                              void* d_out, int out_size, void* d_ws, size_t ws_size,
                              hipStream_t stream) {
    const float* ts      = (const float*)d_in[0];
    const int*   labels  = (const int*)d_in[1];
    const float* amounts = (const float*)d_in[2];
    float* out = (float*)d_out;

    float* Lws = (float*)d_ws;                                   // [32][64][257]
    float* Cws = Lws + (size_t)BATCH * NCHUNK * ROWF;            // [32][64][257]

    dim3 grid(NCHUNK, BATCH);                                    // 64 x 32
    mpe_phase1<<<grid, 128, 0, stream>>>(ts, labels, amounts, Lws);
    const int nrows = BATCH * ROWF;                              // 8224
    mpe_phase2<<<(nrows + 3) / 4, 256, 0, stream>>>(Lws, Cws);
    mpe_phase3<<<grid, 128, 0, stream>>>(ts, labels, amounts, Cws, out);
}

// Round 10
// 149.765 us; speedup vs baseline: 1.1419x; 1.0627x over previous
//
#include <hip/hip_runtime.h>

#define BATCH 32
#define SEQL 4096
#define NCH 128
#define CHUNK 64
#define NCHUNK (SEQL / CHUNK)    // 64 chunks per batch row
#define GSTEP 8                  // output steps per LDS flush group
#define NG (CHUNK / GSTEP)       // 8 groups
#define ROWF 257                 // floats per output row
#define EM 0.9f
#define EM4 0.6561f              // 0.9^4
#define DCH 1.17901846e-3f       // 0.9^64 (chunk decay)
// one-hot (p) side-term constants:
#define C0 0.0729f
#define C1 0.081f
#define C2 0.09f
#define C3 0.1f
// coefficients for pre-scaled (0.1*x) inputs:
#define D0 0.729f
#define D1 0.81f
#define D2 0.9f

// Exact chunk decomposition (EMA is linear), TWO launches:
//   P1: L_k = 64-step local weighted sum per (b,chunk)      [2048 blocks]
//   P3: carry into chunk k = sum_{j=1..4} D^{j-1} L_{k-j}   (Horner, 4 hops;
//       truncation D^4*S ~ 1.9e-12, <=2e-6 after the 1e-6-clip amplification)
//       then evolve 64 steps and store via LDS bounce.
// No P2 scan kernel, no spin/sync: the 4-hop combine makes carries local.
// probs normalizer == 1 (EMA preserves one-hot row sums) => skip it.
// Stores bounce through LDS: row stride 1028 B (≡4 mod 64) would otherwise
// partial-sector RMW at L2/HBM (measured ~12 us penalty in R5->R6).

// ---- phase 1: per-chunk local EMA sums -> Lws[b][k][257] ----
__global__ __launch_bounds__(128) void mpe_phase1(
    const float* __restrict__ ts,
    const int* __restrict__ labels,
    const float* __restrict__ amounts,
    float* __restrict__ Lws)
{
    const int c = threadIdx.x;
    const int k = blockIdx.x;
    const int b = blockIdx.y;
    const int s = k * CHUNK;

    __shared__ float2 s_ad[CHUNK];   // {0.1*amt, 0.1*clipped dt}
    __shared__ int    s_lab[CHUNK];

    const size_t rowbase = (size_t)b * SEQL;
    const float* tsr = ts + rowbase;

    if (c < CHUNK) {
        int gl = s + c;
        float d = (gl > 0) ? fminf(tsr[gl] - tsr[gl - 1], 100.f) : 0.f;
        s_ad[c] = make_float2(0.1f * amounts[rowbase + gl], 0.1f * d);
        s_lab[c] = labels[rowbase + gl];
    }
    __syncthreads();

    float p = 0.f, a = 0.f, dm = 0.f;
    int i = 0;
    if (k == 0) {
        // exact init at global position 0: carry = x[0]
        bool mine = (c == s_lab[0]);
        p = mine ? 1.f : 0.f;
        a = mine ? 10.f * s_ad[0].x : 0.f;   // undo 0.1 pre-scale (~1ulp)
        dm = 0.f;
        i = 1;
    }

    int rem = (CHUNK - i) & 3;               // peel to 4-step alignment
    for (int t = 0; t < rem; ++t, ++i) {
        bool mine = (c == s_lab[i]);
        float2 ad = s_ad[i];
        p = fmaf(p, EM, mine ? 0.1f : 0.f);
        a = fmaf(a, EM, mine ? ad.x : 0.f);
        dm = fmaf(dm, EM, ad.y);
    }
    for (; i < CHUNK; i += 4) {              // grouped: dependent chain cut 4x
        int l0 = s_lab[i], l1 = s_lab[i+1], l2 = s_lab[i+2], l3 = s_lab[i+3];
        float2 a0 = s_ad[i], a1 = s_ad[i+1], a2 = s_ad[i+2], a3 = s_ad[i+3];
        bool m0 = (c == l0), m1 = (c == l1), m2 = (c == l2), m3 = (c == l3);
        float tp = (m0 ? C0 : 0.f) + (m1 ? C1 : 0.f)
                 + (m2 ? C2 : 0.f) + (m3 ? C3 : 0.f);
        float ta = (m0 ? D0 * a0.x : 0.f) + (m1 ? D1 * a1.x : 0.f)
                 + (m2 ? D2 * a2.x : 0.f) + (m3 ? a3.x : 0.f);
        float td = fmaf(D0, a0.y, fmaf(D1, a1.y, fmaf(D2, a2.y, a3.y)));
        p = fmaf(p, EM4, tp);
        a = fmaf(a, EM4, ta);
        dm = fmaf(dm, EM4, td);
    }

    float* Lrow = Lws + ((size_t)b * NCHUNK + k) * ROWF;
    Lrow[1 + c] = p;
    Lrow[1 + NCH + c] = a;
    if (c == 0) Lrow[0] = dm;
}

// ---- phase 3: 4-hop carry combine + outputs; zero warmup, zero scan ----
__global__ __launch_bounds__(128) void mpe_phase3(
    const float* __restrict__ ts,
    const int* __restrict__ labels,
    const float* __restrict__ amounts,
    const float* __restrict__ Lws,
    float* __restrict__ out)
{
    const int c = threadIdx.x;
    const int k = blockIdx.x;
    const int b = blockIdx.y;
    const int s = k * CHUNK;

    __shared__ float2 s_ad[CHUNK];
    __shared__ int    s_lab[CHUNK];
    __shared__ __align__(16) float obuf[GSTEP * ROWF];   // 8224 B

    const size_t rowbase = (size_t)b * SEQL;
    const float* tsr = ts + rowbase;

    if (c < CHUNK) {
        int gl = s + c;
        float d = (gl > 0) ? fminf(tsr[gl] - tsr[gl - 1], 100.f) : 0.f;
        s_ad[c] = make_float2(0.1f * amounts[rowbase + gl], 0.1f * d);
        s_lab[c] = labels[rowbase + gl];
    }

    // carry into this chunk: Horner over up to 4 predecessor L-rows
    // (farthest first). Lws is 2.1 MB -> L2/L3-hot after P1.
    float p = 0.f, a = 0.f, dm = 0.f;
    const int hops = (k < 4) ? k : 4;
    for (int j = hops; j >= 1; --j) {
        const float* Lj = Lws + ((size_t)b * NCHUNK + (k - j)) * ROWF;
        p = fmaf(p, DCH, Lj[1 + c]);
        a = fmaf(a, DCH, Lj[1 + NCH + c]);
        dm = fmaf(dm, DCH, Lj[0]);
    }
    __syncthreads();

    for (int g = 0; g < NG; ++g) {
        const int base = g * GSTEP;
        #pragma unroll
        for (int t = 0; t < GSTEP; ++t) {
            const int idx = base + t;
            if (k == 0 && g == 0 && t == 0) {
                // row 0 is the exact-init state e[0] = x[0]
                bool mine = (c == s_lab[0]);
                p = mine ? 1.f : 0.f;
                a = mine ? 10.f * s_ad[0].x : 0.f;
                dm = 0.f;
            } else {
                bool mine = (c == s_lab[idx]);
                float2 ad = s_ad[idx];
                p = fmaf(p, EM, mine ? 0.1f : 0.f);
                a = fmaf(a, EM, mine ? ad.x : 0.f);
                dm = fmaf(dm, EM, ad.y);
            }
            obuf[t * ROWF + 1 + c] = p;
            obuf[t * ROWF + 1 + NCH + c] = __fdividef(a, fmaxf(p, 1e-6f));
            if (c == 0) obuf[t * ROWF] = dm;
        }
        __syncthreads();

        float4* gout = (float4*)(out + (rowbase + s + base) * (size_t)ROWF);
        const float4* ob4 = (const float4*)obuf;
        for (int q = c; q < GSTEP * ROWF / 4; q += 128)
            gout[q] = ob4[q];
        __syncthreads();
    }
}

extern "C" void kernel_launch(void* const* d_in, const int* in_sizes, int n_in,
                              void* d_out, int out_size, void* d_ws, size_t ws_size,
                              hipStream_t stream) {
    const float* ts      = (const float*)d_in[0];
    const int*   labels  = (const int*)d_in[1];
    const float* amounts = (const float*)d_in[2];
    float* out = (float*)d_out;

    float* Lws = (float*)d_ws;                                   // [32][64][257]

    dim3 grid(NCHUNK, BATCH);                                    // 64 x 32
    mpe_phase1<<<grid, 128, 0, stream>>>(ts, labels, amounts, Lws);
    mpe_phase3<<<grid, 128, 0, stream>>>(ts, labels, amounts, Lws, out);
}